// Round 1
// baseline (65.765 us; speedup 1.0000x reference)
//
#include <hip/hip_runtime.h>
#include <hip/hip_bf16.h>

// out[b, d] = remap_phase(W[labels[b], d] + noise[b, d])
// remap_phase(x) = mod(x + 1, 2) - 1   (wrap into [-1, 1))
//
// B = 262144, D = 128, N_CLASSES = 100000. All fp32 except labels (int32).
// Memory-bound: vectorize as float4 (D = 128 -> 32 float4 per row).
// 32 consecutive lanes share one row -> label load broadcasts via L1,
// W row read is fully coalesced; W (51 MB) stays resident in L3.

__global__ void __launch_bounds__(256) label_encoder_kernel(
    const int* __restrict__ labels,
    const float* __restrict__ W,       // [N_CLASSES, 128]
    const float* __restrict__ noise,   // [B, 128]
    float* __restrict__ out,           // [B, 128]
    long long n_vec4)                  // B * 32
{
    const long long stride = (long long)gridDim.x * blockDim.x;
    for (long long g = (long long)blockIdx.x * blockDim.x + threadIdx.x;
         g < n_vec4; g += stride) {
        const long long row  = g >> 5;        // / 32 float4 per row
        const int       col4 = (int)(g & 31); // float4 index within row

        const int lab = labels[row];

        const float4 w = *reinterpret_cast<const float4*>(
            W + (long long)lab * 128 + (long long)col4 * 4);
        const float4 nz = *reinterpret_cast<const float4*>(
            noise + row * 128 + (long long)col4 * 4);

        float4 r;
        {
            float y;
            y = w.x + nz.x + 1.0f; r.x = y - 2.0f * floorf(y * 0.5f) - 1.0f;
            y = w.y + nz.y + 1.0f; r.y = y - 2.0f * floorf(y * 0.5f) - 1.0f;
            y = w.z + nz.z + 1.0f; r.z = y - 2.0f * floorf(y * 0.5f) - 1.0f;
            y = w.w + nz.w + 1.0f; r.w = y - 2.0f * floorf(y * 0.5f) - 1.0f;
        }

        *reinterpret_cast<float4*>(out + row * 128 + (long long)col4 * 4) = r;
    }
}

extern "C" void kernel_launch(void* const* d_in, const int* in_sizes, int n_in,
                              void* d_out, int out_size, void* d_ws, size_t ws_size,
                              hipStream_t stream) {
    const int*   labels = (const int*)d_in[0];    // [B]
    const float* W      = (const float*)d_in[1];  // [N_CLASSES, 128]
    const float* noise  = (const float*)d_in[2];  // [B, 128]
    float*       out    = (float*)d_out;          // [B, 128]

    const long long n_vec4 = (long long)out_size / 4;  // B*128/4

    const int block = 256;
    const int grid  = 2048;  // grid-stride; ~8 blocks/CU across 256 CUs
    label_encoder_kernel<<<grid, block, 0, stream>>>(labels, W, noise, out, n_vec4);
}